// Round 6
// baseline (261.858 us; speedup 1.0000x reference)
//
#include <hip/hip_runtime.h>
#include <math.h>

// SparseGate: B=16384, D=2048, E=64, k=2
// R6: occupancy/barrier-domain fix. R5's fused64 (77 us) was latency-bound
// (MfmaUtil 13%, VALU 21%, HBM 13%) with 96 KB LDS -> 1 block/CU -> ONE
// 16-wave barrier domain: any wave's memory stall idles the whole CU.
// R6: block = 32 rows x 512 thr = 2 K-groups x 4 waves, wave = 32r x 32c
// (acc[2][2], no B column duplication -> B-L2 halved to 1 MB/block),
// LDS ~50 KB (padded, conflict-free) -> 2 blocks/CU = 2 independent
// barrier domains co-scheduling (m114 overlap). Inner-loop conventions
// (fragments, 3-pass hi/lo bf16, depth-1 B prefetch) verbatim from R5.
#define NROWS 16384
#define DDIM  2048
#define NEXP  64
#define NCOL  128            // fused: 64 gate cols + 64 noise cols

constexpr float TAU = 1e-3f;        // margin below which we recheck in fp32

typedef __attribute__((ext_vector_type(8))) short short8;
typedef __attribute__((ext_vector_type(4))) short shortx4;
typedef __attribute__((ext_vector_type(4))) float floatx4;

// ---------------- fp32 -> bf16 hi/lo truncation split ----------------
__device__ __forceinline__ void split8(const float4 a, const float4 b,
                                       short8* hi, short8* lo)
{
    float f[8] = {a.x, a.y, a.z, a.w, b.x, b.y, b.z, b.w};
    union { unsigned short u[8]; short8 v; } H, L;
    #pragma unroll
    for (int j = 0; j < 8; ++j) {
        const unsigned int u  = __float_as_uint(f[j]);
        const unsigned int hf = u & 0xFFFF0000u;
        const float lf = f[j] - __uint_as_float(hf);   // exact
        H.u[j] = (unsigned short)(u >> 16);
        L.u[j] = (unsigned short)(__float_as_uint(lf) >> 16);
    }
    *hi = H.v; *lo = L.v;
}

__device__ __forceinline__ void split4(const float4 a, shortx4* hi, shortx4* lo)
{
    float f[4] = {a.x, a.y, a.z, a.w};
    union { unsigned short u[4]; shortx4 v; } H, L;
    #pragma unroll
    for (int j = 0; j < 4; ++j) {
        const unsigned int u  = __float_as_uint(f[j]);
        const unsigned int hf = u & 0xFFFF0000u;
        const float lf = f[j] - __uint_as_float(hf);   // exact
        H.u[j] = (unsigned short)(u >> 16);
        L.u[j] = (unsigned short)(__float_as_uint(lf) >> 16);
    }
    *hi = H.v; *lo = L.v;
}

__device__ __forceinline__ float softplus_f(float x) {
    return fmaxf(x, 0.f) + log1pf(expf(-fabsf(x)));
}

// ---------------- top-k + softmax over a 64-lane row ----------------
__device__ __forceinline__ float row_gate(int lane, float ew, int k, float* margin)
{
    float cur = ew;
    const float myv = ew;
    float m0 = 0.f, denom = 0.f, vk = 0.f, vk1 = 0.f;
    int selected = 0;
    const int iters = (k < NEXP) ? (k + 1) : k;
    for (int t = 0; t < iters; ++t) {
        float v = cur;
        int idx = lane;
        #pragma unroll
        for (int off = 32; off; off >>= 1) {
            const float ov = __shfl_xor(v, off);
            const int   oi = __shfl_xor(idx, off);
            if (ov > v || (ov == v && oi < idx)) { v = ov; idx = oi; }
        }
        if (t == 0) m0 = v;
        if (t < k) {
            denom += expf(v - m0);
            vk = v;
            if (lane == idx) { selected = 1; cur = -INFINITY; }
        } else {
            vk1 = v;
        }
    }
    *margin = (k < NEXP) ? (vk - vk1) : 1e30f;
    return selected ? expf(myv - m0) / denom : 0.f;
}

// ---------------- weight prep: pack B in exact wave-read order ----------------
// UNCHANGED (verified). Bpk short index:
//   (((kt*8 + ct)*2 + h)*64 + ln)*8 + j   (1 MB total)
// value = bf16 part h of W[col = ct*16 + (ln&15)][k = kt*32 + (ln>>4)*8 + j]
__global__ __launch_bounds__(256) void wprep_kernel(
    const float* __restrict__ gw, const float* __restrict__ nw,
    unsigned short* __restrict__ bpk, int* __restrict__ counter)
{
    const int g = blockIdx.x * 256 + threadIdx.x;    // 0..32767
    if (g == 0) counter[0] = 0;
    const int kt = g >> 9;            // 0..63
    const int ct = (g >> 6) & 7;      // 0..7
    const int ln = g & 63;            // 0..63
    const int col = ct * 16 + (ln & 15);
    const int kb  = kt * 32 + (ln >> 4) * 8;
    const float* src = (col < NEXP) ? (gw + (size_t)col * DDIM)
                                    : (nw + (size_t)(col - NEXP) * DDIM);
    src += kb;
    const float4 a = *(const float4*)src;
    const float4 b = *(const float4*)(src + 4);
    short8 hi, lo;
    split8(a, b, &hi, &lo);
    const size_t base = ((size_t)(kt * 8 + ct) * 2) * 512 + (size_t)ln * 8;
    *(short8*)&bpk[base]       = hi;    // h=0
    *(short8*)&bpk[base + 512] = lo;    // h=1
}

// ---------------- fused 32-row in-block-split-K GEMM + gate ----------------
// Block = 32 rows x 128 cols x K=2048, 512 threads = 8 waves:
//   kg = wid>>2 (K-half, 1024 k), wv = wid&3 (wave tile 32 rows x 32 cols,
//   ct = wv*2 + {0,1}: no two waves read the same B fragments).
// Per kg: private double-buffered A staging (32 rows x 32 k bf16 hi/lo,
// padded rows: 33*16 B stride -> conflict-free writes AND reads).
// kit = 32 iterations of 32-k per kg; depth-1 B register prefetch.
// Epilogue: 2 phased LDS adds -> ew[32][132] -> per-wave gate on 4 rows.
__global__ __launch_bounds__(512, 6) void fused32_kernel(
    const float* __restrict__ x,
    const unsigned short* __restrict__ bpk,
    const float* __restrict__ noise,
    const int* __restrict__ kptr,
    float* __restrict__ out,
    int* __restrict__ counter,
    int* __restrict__ list)
{
    // [kg][buf][h][kq][row(33 pad)][8 shorts] = 33792 B
    __shared__ __align__(16) unsigned short ldsA[2][2][2][4][33][8];
    __shared__ float ew[32][132];    // 16896 B (pad 132: quads hit distinct banks)

    const int tid  = threadIdx.x;
    const int wid  = tid >> 6;          // 0..7
    const int kg   = wid >> 2;          // K-half 0..1
    const int wv   = wid & 3;           // wave within kg
    const int ln   = tid & 63;
    const int l15  = ln & 15;
    const int quad = ln >> 4;

    const int rowbase = blockIdx.x * 32;         // grid.x = 512

    // staging: kg's 256 threads each stage 4 floats per kt:
    //   st_r = (t>>3) (32 rows), floats (t&7)*4 -> kq=(t&7)>>1, half=t&1
    const int kgt  = tid & 255;
    const int st_r = kgt >> 3;
    const int st_kq   = (kgt & 7) >> 1;
    const int st_half = kgt & 1;
    const float* xs = x + (size_t)(rowbase + st_r) * DDIM + kg * 1024
                        + st_kq * 8 + st_half * 4;

    const short8* bp = (const short8*)bpk;       // idx = ((kt*8+ct)*2+h)*64 + ln
    const int ct0 = wv * 2;                      // this wave's first col-16 tile
    const int kt0 = kg * 32;                     // first 32-k slice of this kg

    floatx4 acc[2][2];
    #pragma unroll
    for (int rt = 0; rt < 2; ++rt)
        #pragma unroll
        for (int ct = 0; ct < 2; ++ct)
            acc[rt][ct] = (floatx4){0.f, 0.f, 0.f, 0.f};

    // preamble: A(0) regs, B(0) regs
    float4 ar = *(const float4*)(xs);
    short8 bcur[2][2];
    #pragma unroll
    for (int ct = 0; ct < 2; ++ct) {
        bcur[ct][0] = bp[(size_t)((kt0 * 8 + ct0 + ct) * 2 + 0) * 64 + ln];
        bcur[ct][1] = bp[(size_t)((kt0 * 8 + ct0 + ct) * 2 + 1) * 64 + ln];
    }

    constexpr int kit = 32;                      // 32 x 32-k = 1024 k per kg
    for (int kt = 0; kt < kit; ++kt) {
        const int buf = kt & 1;
        // ---- stage A(kt): consume reg (vmcnt wait), convert, LDS write ----
        {
            shortx4 hi, lo;
            split4(ar, &hi, &lo);
            *(shortx4*)&ldsA[kg][buf][0][st_kq][st_r][st_half * 4] = hi;
            *(shortx4*)&ldsA[kg][buf][1][st_kq][st_r][st_half * 4] = lo;
        }
        __syncthreads();   // both kgs in lockstep; dbuf isolates readers

        // ---- issue A(kt+1) now (flies during MFMA phase) ----
        if (kt + 1 < kit) {
            ar = *(const float4*)(xs + (kt + 1) * 32);
        }

        // ---- A fragments from LDS (rows rt*16 + l15, k-group = quad) ----
        short8 ahi[2], alo[2];
        #pragma unroll
        for (int rt = 0; rt < 2; ++rt) {
            const int row = rt * 16 + l15;
            ahi[rt] = *(const short8*)&ldsA[kg][buf][0][quad][row][0];
            alo[rt] = *(const short8*)&ldsA[kg][buf][1][quad][row][0];
        }

        // ---- MFMA: consume bcur, prefetch B(kt+1) per-ct ----
        const int ktg = kt0 + kt;
        #pragma unroll
        for (int ct = 0; ct < 2; ++ct) {
            const short8 bh = bcur[ct][0];
            const short8 bl = bcur[ct][1];
            if (kt + 1 < kit) {
                bcur[ct][0] = bp[(size_t)(((ktg + 1) * 8 + ct0 + ct) * 2 + 0) * 64 + ln];
                bcur[ct][1] = bp[(size_t)(((ktg + 1) * 8 + ct0 + ct) * 2 + 1) * 64 + ln];
            }
            acc[0][ct] = __builtin_amdgcn_mfma_f32_16x16x32_bf16(ahi[0], bh, acc[0][ct], 0, 0, 0);
            acc[1][ct] = __builtin_amdgcn_mfma_f32_16x16x32_bf16(ahi[1], bh, acc[1][ct], 0, 0, 0);
            acc[0][ct] = __builtin_amdgcn_mfma_f32_16x16x32_bf16(ahi[0], bl, acc[0][ct], 0, 0, 0);
            acc[1][ct] = __builtin_amdgcn_mfma_f32_16x16x32_bf16(ahi[1], bl, acc[1][ct], 0, 0, 0);
            acc[0][ct] = __builtin_amdgcn_mfma_f32_16x16x32_bf16(alo[0], bh, acc[0][ct], 0, 0, 0);
            acc[1][ct] = __builtin_amdgcn_mfma_f32_16x16x32_bf16(alo[1], bh, acc[1][ct], 0, 0, 0);
        }
    }

    // ---- phased partial reduce into ew (C/D: col=l15, row=quad*4+reg) ----
    __syncthreads();
    #pragma unroll
    for (int p = 0; p < 2; ++p) {
        if (kg == p) {
            #pragma unroll
            for (int rt = 0; rt < 2; ++rt)
                #pragma unroll
                for (int r = 0; r < 4; ++r) {
                    const int row = rt * 16 + quad * 4 + r;
                    #pragma unroll
                    for (int ct = 0; ct < 2; ++ct) {
                        const int col = (ct0 + ct) * 16 + l15;
                        if (p == 0) ew[row][col]  = acc[rt][ct][r];
                        else        ew[row][col] += acc[rt][ct][r];
                    }
                }
        }
        __syncthreads();
    }

    // ---- gate: 8 waves x 4 rows each ----
    int k = kptr[0];
    if (k < 1) k = 1;
    if (k > NEXP) k = NEXP;

    #pragma unroll
    for (int rr = 0; rr < 4; ++rr) {
        const int row  = wid * 4 + rr;
        const int grow = rowbase + row;
        const float clean = ew[row][ln];
        const float noisy = ew[row][NEXP + ln];
        const float nz    = noise[(size_t)grow * NEXP + ln];
        const float ewv   = clean + nz * softplus_f(noisy);
        float margin;
        const float val = row_gate(ln, ewv, k, &margin);
        out[(size_t)grow * NEXP + ln] = val;
        if (margin < TAU && ln == 0) {
            const int pos = atomicAdd(counter, 1);
            list[pos] = grow;
        }
    }
}

// ---------------- exact fp32 recheck for low-margin rows ----------------
__global__ __launch_bounds__(256) void recheck_kernel(
    const float* __restrict__ x,
    const float* __restrict__ gw,
    const float* __restrict__ nw,
    const float* __restrict__ noise,
    const int* __restrict__ kptr,
    float* __restrict__ out,
    const int* __restrict__ counter,
    const int* __restrict__ list)
{
    __shared__ float xr[DDIM];      // 8 KB
    __shared__ float parts[256];
    __shared__ float lg[NCOL];

    const int tid = threadIdx.x;
    const int cnt = counter[0];

    int k = kptr[0];
    if (k < 1) k = 1;
    if (k > NEXP) k = NEXP;

    for (int ii = blockIdx.x; ii < cnt; ii += gridDim.x) {
        const int row = list[ii];
        const float4* xs = (const float4*)(x + (size_t)row * DDIM);
        #pragma unroll
        for (int j = 0; j < 2; ++j)
            ((float4*)xr)[tid + j * 256] = xs[tid + j * 256];
        __syncthreads();

        const int e = tid & 127;
        const int half = tid >> 7;
        const float* wc = (e < NEXP) ? (gw + (size_t)e * DDIM)
                                     : (nw + (size_t)(e - NEXP) * DDIM);
        wc += half * 1024;
        const float* xc = xr + half * 1024;
        float s = 0.f;
        #pragma unroll 4
        for (int j = 0; j < 1024; j += 4) {
            float4 w4 = *(const float4*)&wc[j];
            s += xc[j] * w4.x + xc[j + 1] * w4.y + xc[j + 2] * w4.z + xc[j + 3] * w4.w;
        }
        parts[tid] = s;
        __syncthreads();
        if (tid < NCOL) lg[tid] = parts[tid] + parts[tid + 128];
        __syncthreads();
        if (tid < NEXP) {
            const float ew = lg[tid] + noise[(size_t)row * NEXP + tid] * softplus_f(lg[NEXP + tid]);
            float margin;
            const float val = row_gate(tid, ew, k, &margin);
            out[(size_t)row * NEXP + tid] = val;
        }
        __syncthreads();
    }
}

// ---------------- fallback: exact per-row (only if ws too small) ----------------
__global__ __launch_bounds__(256) void naive_kernel(
    const float* __restrict__ x,
    const float* __restrict__ gw,
    const float* __restrict__ nw,
    const float* __restrict__ noise,
    const int* __restrict__ kptr,
    float* __restrict__ out)
{
    const int lane = threadIdx.x & 63;
    const int wave = threadIdx.x >> 6;
    const int row  = blockIdx.x * 4 + wave;
    if (row >= NROWS) return;

    int k = kptr[0];
    if (k < 1) k = 1;
    if (k > NEXP) k = NEXP;

    const float* xr = x  + (size_t)row  * DDIM;
    const float* g  = gw + (size_t)lane * DDIM;
    const float* w2 = nw + (size_t)lane * DDIM;
    float c = 0.f, n = 0.f;
    for (int d = 0; d < DDIM; ++d) {
        const float xv = xr[d];
        c += xv * g[d];
        n += xv * w2[d];
    }
    const float ew = c + noise[(size_t)row * NEXP + lane] * softplus_f(n);
    float margin;
    out[(size_t)row * NEXP + lane] = row_gate(lane, ew, k, &margin);
}

// ---------------------------------------------------------------------------
extern "C" void kernel_launch(void* const* d_in, const int* in_sizes, int n_in,
                              void* d_out, int out_size, void* d_ws, size_t ws_size,
                              hipStream_t stream)
{
    const float* x     = (const float*)d_in[0];
    const float* gw    = (const float*)d_in[1];
    const float* nw    = (const float*)d_in[2];
    const float* noise = (const float*)d_in[3];
    const int*   kptr  = (const int*)d_in[4];
    float* out = (float*)d_out;

    // ws: bpk (1 MB) | counter (256 B) | list (64 KB)
    const size_t BPK_BYTES = (size_t)NCOL * DDIM * 2 * sizeof(unsigned short); // 1 MB
    const size_t TAIL      = 256 + NROWS * sizeof(int);

    if (ws_size < BPK_BYTES + TAIL) {
        hipLaunchKernelGGL(naive_kernel, dim3(NROWS / 4), dim3(256), 0, stream,
                           x, gw, nw, noise, kptr, out);
        return;
    }

    unsigned short* bpk     = (unsigned short*)d_ws;
    int*            counter = (int*)((char*)d_ws + BPK_BYTES);
    int*            list    = counter + 64;

    hipLaunchKernelGGL(wprep_kernel, dim3(128), dim3(256), 0, stream,
                       gw, nw, bpk, counter);
    hipLaunchKernelGGL(fused32_kernel, dim3(NROWS / 32), dim3(512), 0, stream,
                       x, bpk, noise, kptr, out, counter, list);
    hipLaunchKernelGGL(recheck_kernel, dim3(256), dim3(256), 0, stream,
                       x, gw, nw, noise, kptr, out, counter, list);
}

// Round 8
// 256.479 us; speedup vs baseline: 1.0210x; 1.0210x over previous
//
#include <hip/hip_runtime.h>
#include <math.h>

// SparseGate: B=16384, D=2048, E=64, k=2
// R8: identical resubmission of R7 (never benched - infra died twice).
// Theory under test: x-ingest granularity. R4/R5/R6 invariant: dur ~= FETCH /
// 0.9 TB/s while fills hit 6.8 TB/s -> all prior variants read x as 64-128 B
// fragments at exactly 8 KB stride (row pitch) = channel-interleave hotspot.
// fusedC: stage A in CK=256-k super-iterations; each load instruction is
// ONE row x 1 KB lane-contiguous (m13 pattern). 16 waves = 2 rg x 8 cg,
// wave = 32r x 16c, full K per block, single-buffer LDS + register prefetch.
// Numerics identical to verified R5/R6 (hi/lo split, 3-pass MFMA, same gate).
#define NROWS 16384
#define DDIM  2048
#define NEXP  64
#define NCOL  128            // fused: 64 gate cols + 64 noise cols

constexpr float TAU = 1e-3f;        // margin below which we recheck in fp32

typedef __attribute__((ext_vector_type(8))) short short8;
typedef __attribute__((ext_vector_type(4))) short shortx4;
typedef __attribute__((ext_vector_type(4))) float floatx4;

// ---------------- fp32 -> bf16 hi/lo truncation split ----------------
__device__ __forceinline__ void split8(const float4 a, const float4 b,
                                       short8* hi, short8* lo)
{
    float f[8] = {a.x, a.y, a.z, a.w, b.x, b.y, b.z, b.w};
    union { unsigned short u[8]; short8 v; } H, L;
    #pragma unroll
    for (int j = 0; j < 8; ++j) {
        const unsigned int u  = __float_as_uint(f[j]);
        const unsigned int hf = u & 0xFFFF0000u;
        const float lf = f[j] - __uint_as_float(hf);   // exact
        H.u[j] = (unsigned short)(u >> 16);
        L.u[j] = (unsigned short)(__float_as_uint(lf) >> 16);
    }
    *hi = H.v; *lo = L.v;
}

__device__ __forceinline__ void split4(const float4 a, shortx4* hi, shortx4* lo)
{
    float f[4] = {a.x, a.y, a.z, a.w};
    union { unsigned short u[4]; shortx4 v; } H, L;
    #pragma unroll
    for (int j = 0; j < 4; ++j) {
        const unsigned int u  = __float_as_uint(f[j]);
        const unsigned int hf = u & 0xFFFF0000u;
        const float lf = f[j] - __uint_as_float(hf);   // exact
        H.u[j] = (unsigned short)(u >> 16);
        L.u[j] = (unsigned short)(__float_as_uint(lf) >> 16);
    }
    *hi = H.v; *lo = L.v;
}

__device__ __forceinline__ float softplus_f(float x) {
    return fmaxf(x, 0.f) + log1pf(expf(-fabsf(x)));
}

// ---------------- top-k + softmax over a 64-lane row ----------------
__device__ __forceinline__ float row_gate(int lane, float ew, int k, float* margin)
{
    float cur = ew;
    const float myv = ew;
    float m0 = 0.f, denom = 0.f, vk = 0.f, vk1 = 0.f;
    int selected = 0;
    const int iters = (k < NEXP) ? (k + 1) : k;
    for (int t = 0; t < iters; ++t) {
        float v = cur;
        int idx = lane;
        #pragma unroll
        for (int off = 32; off; off >>= 1) {
            const float ov = __shfl_xor(v, off);
            const int   oi = __shfl_xor(idx, off);
            if (ov > v || (ov == v && oi < idx)) { v = ov; idx = oi; }
        }
        if (t == 0) m0 = v;
        if (t < k) {
            denom += expf(v - m0);
            vk = v;
            if (lane == idx) { selected = 1; cur = -INFINITY; }
        } else {
            vk1 = v;
        }
    }
    *margin = (k < NEXP) ? (vk - vk1) : 1e30f;
    return selected ? expf(myv - m0) / denom : 0.f;
}

// ---------------- weight prep: pack B in exact wave-read order ----------------
// UNCHANGED (verified). Bpk short index:
//   (((kt*8 + ct)*2 + h)*64 + ln)*8 + j   (1 MB total)
// value = bf16 part h of W[col = ct*16 + (ln&15)][k = kt*32 + (ln>>4)*8 + j]
__global__ __launch_bounds__(256) void wprep_kernel(
    const float* __restrict__ gw, const float* __restrict__ nw,
    unsigned short* __restrict__ bpk, int* __restrict__ counter)
{
    const int g = blockIdx.x * 256 + threadIdx.x;    // 0..32767
    if (g == 0) counter[0] = 0;
    const int kt = g >> 9;            // 0..63
    const int ct = (g >> 6) & 7;      // 0..7
    const int ln = g & 63;            // 0..63
    const int col = ct * 16 + (ln & 15);
    const int kb  = kt * 32 + (ln >> 4) * 8;
    const float* src = (col < NEXP) ? (gw + (size_t)col * DDIM)
                                    : (nw + (size_t)(col - NEXP) * DDIM);
    src += kb;
    const float4 a = *(const float4*)src;
    const float4 b = *(const float4*)(src + 4);
    short8 hi, lo;
    split8(a, b, &hi, &lo);
    const size_t base = ((size_t)(kt * 8 + ct) * 2) * 512 + (size_t)ln * 8;
    *(short8*)&bpk[base]       = hi;    // h=0
    *(short8*)&bpk[base + 512] = lo;    // h=1
}

// ---------------- fused full-K GEMM + gate, contiguous x staging ----------
// Block = 64 rows x 128 cols x K=2048; 1024 threads = 16 waves:
//   cg = wid&7 (16-col group, ct = cg), rg = wid>>3 (32-row group).
// 8 super-iterations of CK=256 k:
//   stage: wave w loads rows w*4..w*4+3, each as ONE 1-KB lane-contiguous
//          float4 load (lane l -> k = l*4) -> split4 -> 2 ds_write_b64
//          into ldsA[h][kq(32)][row(pad 65)][8]  (reads conflict-free)
//   compute: 8 x 32-k steps; per step 4 ds_read_b128 A-frags + depth-1
//            B register prefetch + 6 MFMA (acc[2], rows rg*32+rt*16).
//   A(si+1) issued into regs right after the post-write barrier.
// Epilogue: acc -> ew[64][132] -> 16 waves x 4 rows gate -> out + margin list.
__global__ __launch_bounds__(1024, 4) void fusedC_kernel(
    const float* __restrict__ x,
    const unsigned short* __restrict__ bpk,
    const float* __restrict__ noise,
    const int* __restrict__ kptr,
    float* __restrict__ out,
    int* __restrict__ counter,
    int* __restrict__ list)
{
    __shared__ __align__(16) unsigned short ldsA[2][32][65][8];  // 66,560 B
    __shared__ float ew[64][132];                                // 33,792 B

    const int tid  = threadIdx.x;
    const int wid  = tid >> 6;          // 0..15
    const int cg   = wid & 7;           // col-16 group (= bpk ct)
    const int rg   = wid >> 3;          // row-32 group
    const int ln   = tid & 63;
    const int l15  = ln & 15;
    const int quad = ln >> 4;

    const int rowbase = blockIdx.x * 64;         // grid.x = 256

    // staging: wave stages rows sr0..sr0+3; lane l holds k = l*4..l*4+3
    const int sr0 = wid * 4;
    const float* xrow = x + (size_t)(rowbase + sr0) * DDIM + ln * 4;
    const int wkq  = ln >> 1;           // write kq
    const int wpos = (ln & 1) * 4;      // write short offset

    const short8* bp = (const short8*)bpk;       // idx = ((kt*8+ct)*2+h)*64 + ln

    floatx4 acc[2];
    acc[0] = (floatx4){0.f, 0.f, 0.f, 0.f};
    acc[1] = (floatx4){0.f, 0.f, 0.f, 0.f};

    // prologue: A(si=0) regs (4 x 1-KB contiguous loads), B(kt=0) regs
    float4 ar[4];
    #pragma unroll
    for (int c = 0; c < 4; ++c)
        ar[c] = *(const float4*)(xrow + (size_t)c * DDIM);

    short8 bcur[2];
    bcur[0] = bp[(size_t)((0 * 8 + cg) * 2 + 0) * 64 + ln];
    bcur[1] = bp[(size_t)((0 * 8 + cg) * 2 + 1) * 64 + ln];

    for (int si = 0; si < 8; ++si) {
        // ---- write A(si): consume ar (vmcnt wait), convert, LDS write ----
        #pragma unroll
        for (int c = 0; c < 4; ++c) {
            shortx4 hi, lo;
            split4(ar[c], &hi, &lo);
            *(shortx4*)&ldsA[0][wkq][sr0 + c][wpos] = hi;
            *(shortx4*)&ldsA[1][wkq][sr0 + c][wpos] = lo;
        }
        __syncthreads();                 // tile visible to all waves

        // ---- issue A(si+1): flies over the 8-step MFMA phase ----
        if (si + 1 < 8) {
            #pragma unroll
            for (int c = 0; c < 4; ++c)
                ar[c] = *(const float4*)(xrow + (size_t)c * DDIM + (si + 1) * 256);
        }

        // ---- 8 x 32-k steps ----
        #pragma unroll
        for (int step = 0; step < 8; ++step) {
            const int kq = step * 4 + quad;
            short8 ahi[2], alo[2];
            #pragma unroll
            for (int rt = 0; rt < 2; ++rt) {
                const int row = rg * 32 + rt * 16 + l15;
                ahi[rt] = *(const short8*)&ldsA[0][kq][row][0];
                alo[rt] = *(const short8*)&ldsA[1][kq][row][0];
            }
            const int kt = si * 8 + step;
            const short8 bh = bcur[0];
            const short8 bl = bcur[1];
            if (kt + 1 < 64) {
                bcur[0] = bp[(size_t)(((kt + 1) * 8 + cg) * 2 + 0) * 64 + ln];
                bcur[1] = bp[(size_t)(((kt + 1) * 8 + cg) * 2 + 1) * 64 + ln];
            }
            acc[0] = __builtin_amdgcn_mfma_f32_16x16x32_bf16(ahi[0], bh, acc[0], 0, 0, 0);
            acc[1] = __builtin_amdgcn_mfma_f32_16x16x32_bf16(ahi[1], bh, acc[1], 0, 0, 0);
            acc[0] = __builtin_amdgcn_mfma_f32_16x16x32_bf16(ahi[0], bl, acc[0], 0, 0, 0);
            acc[1] = __builtin_amdgcn_mfma_f32_16x16x32_bf16(ahi[1], bl, acc[1], 0, 0, 0);
            acc[0] = __builtin_amdgcn_mfma_f32_16x16x32_bf16(alo[0], bh, acc[0], 0, 0, 0);
            acc[1] = __builtin_amdgcn_mfma_f32_16x16x32_bf16(alo[1], bh, acc[1], 0, 0, 0);
        }
        __syncthreads();                 // reads done; next write safe
    }

    // ---- epilogue: acc -> ew (C/D: col=l15, row=quad*4+reg) ----
    #pragma unroll
    for (int rt = 0; rt < 2; ++rt) {
        const int col = cg * 16 + l15;
        #pragma unroll
        for (int r = 0; r < 4; ++r)
            ew[rg * 32 + rt * 16 + quad * 4 + r][col] = acc[rt][r];
    }
    __syncthreads();

    // ---- gate: 16 waves x 4 rows each ----
    int k = kptr[0];
    if (k < 1) k = 1;
    if (k > NEXP) k = NEXP;

    #pragma unroll
    for (int rr = 0; rr < 4; ++rr) {
        const int row  = wid * 4 + rr;
        const int grow = rowbase + row;
        const float clean = ew[row][ln];
        const float noisy = ew[row][NEXP + ln];
        const float nz    = noise[(size_t)grow * NEXP + ln];
        const float ewv   = clean + nz * softplus_f(noisy);
        float margin;
        const float val = row_gate(ln, ewv, k, &margin);
        out[(size_t)grow * NEXP + ln] = val;
        if (margin < TAU && ln == 0) {
            const int pos = atomicAdd(counter, 1);
            list[pos] = grow;
        }
    }
}

// ---------------- exact fp32 recheck for low-margin rows ----------------
__global__ __launch_bounds__(256) void recheck_kernel(
    const float* __restrict__ x,
    const float* __restrict__ gw,
    const float* __restrict__ nw,
    const float* __restrict__ noise,
    const int* __restrict__ kptr,
    float* __restrict__ out,
    const int* __restrict__ counter,
    const int* __restrict__ list)
{
    __shared__ float xr[DDIM];      // 8 KB
    __shared__ float parts[256];
    __shared__ float lg[NCOL];

    const int tid = threadIdx.x;
    const int cnt = counter[0];

    int k = kptr[0];
    if (k < 1) k = 1;
    if (k > NEXP) k = NEXP;

    for (int ii = blockIdx.x; ii < cnt; ii += gridDim.x) {
        const int row = list[ii];
        const float4* xs = (const float4*)(x + (size_t)row * DDIM);
        #pragma unroll
        for (int j = 0; j < 2; ++j)
            ((float4*)xr)[tid + j * 256] = xs[tid + j * 256];
        __syncthreads();

        const int e = tid & 127;
        const int half = tid >> 7;
        const float* wc = (e < NEXP) ? (gw + (size_t)e * DDIM)
                                     : (nw + (size_t)(e - NEXP) * DDIM);
        wc += half * 1024;
        const float* xc = xr + half * 1024;
        float s = 0.f;
        #pragma unroll 4
        for (int j = 0; j < 1024; j += 4) {
            float4 w4 = *(const float4*)&wc[j];
            s += xc[j] * w4.x + xc[j + 1] * w4.y + xc[j + 2] * w4.z + xc[j + 3] * w4.w;
        }
        parts[tid] = s;
        __syncthreads();
        if (tid < NCOL) lg[tid] = parts[tid] + parts[tid + 128];
        __syncthreads();
        if (tid < NEXP) {
            const float ew = lg[tid] + noise[(size_t)row * NEXP + tid] * softplus_f(lg[NEXP + tid]);
            float margin;
            const float val = row_gate(tid, ew, k, &margin);
            out[(size_t)row * NEXP + tid] = val;
        }
        __syncthreads();
    }
}

// ---------------- fallback: exact per-row (only if ws too small) ----------------
__global__ __launch_bounds__(256) void naive_kernel(
    const float* __restrict__ x,
    const float* __restrict__ gw,
    const float* __restrict__ nw,
    const float* __restrict__ noise,
    const int* __restrict__ kptr,
    float* __restrict__ out)
{
    const int lane = threadIdx.x & 63;
    const int wave = threadIdx.x >> 6;
    const int row  = blockIdx.x * 4 + wave;
    if (row >= NROWS) return;

    int k = kptr[0];
    if (k < 1) k = 1;
    if (k > NEXP) k = NEXP;

    const float* xr = x  + (size_t)row  * DDIM;
    const float* g  = gw + (size_t)lane * DDIM;
    const float* w2 = nw + (size_t)lane * DDIM;
    float c = 0.f, n = 0.f;
    for (int d = 0; d < DDIM; ++d) {
        const float xv = xr[d];
        c += xv * g[d];
        n += xv * w2[d];
    }
    const float ew = c + noise[(size_t)row * NEXP + lane] * softplus_f(n);
    float margin;
    out[(size_t)row * NEXP + lane] = row_gate(lane, ew, k, &margin);
}

// ---------------------------------------------------------------------------
extern "C" void kernel_launch(void* const* d_in, const int* in_sizes, int n_in,
                              void* d_out, int out_size, void* d_ws, size_t ws_size,
                              hipStream_t stream)
{
    const float* x     = (const float*)d_in[0];
    const float* gw    = (const float*)d_in[1];
    const float* nw    = (const float*)d_in[2];
    const float* noise = (const float*)d_in[3];
    const int*   kptr  = (const int*)d_in[4];
    float* out = (float*)d_out;

    // ws: bpk (1 MB) | counter (256 B) | list (64 KB)
    const size_t BPK_BYTES = (size_t)NCOL * DDIM * 2 * sizeof(unsigned short); // 1 MB
    const size_t TAIL      = 256 + NROWS * sizeof(int);

    if (ws_size < BPK_BYTES + TAIL) {
        hipLaunchKernelGGL(naive_kernel, dim3(NROWS / 4), dim3(256), 0, stream,
                           x, gw, nw, noise, kptr, out);
        return;
    }

    unsigned short* bpk     = (unsigned short*)d_ws;
    int*            counter = (int*)((char*)d_ws + BPK_BYTES);
    int*            list    = counter + 64;

    hipLaunchKernelGGL(wprep_kernel, dim3(128), dim3(256), 0, stream,
                       gw, nw, bpk, counter);
    hipLaunchKernelGGL(fusedC_kernel, dim3(NROWS / 64), dim3(1024), 0, stream,
                       x, bpk, noise, kptr, out, counter, list);
    hipLaunchKernelGGL(recheck_kernel, dim3(256), dim3(256), 0, stream,
                       x, gw, nw, noise, kptr, out, counter, list);
}